// Round 14
// baseline (830.801 us; speedup 1.0000x reference)
//
#include <hip/hip_runtime.h>

typedef __bf16 bf16_t;
typedef bf16_t bf16x8 __attribute__((ext_vector_type(8)));
typedef float  f32x4  __attribute__((ext_vector_type(4)));

#define MFMA16(A, B, C) __builtin_amdgcn_mfma_f32_16x16x32_bf16((A), (B), (C), 0, 0, 0)

static constexpr int KEXT   = 288;  // 256 h | 3 x | 1 ones(bias) | 28 zero pad
static constexpr int HS     = 296;  // hx LDS row stride
static constexpr int GS     = 264;  // gate-g LDS tile stride
static constexpr int TSTEPS = 128;
static constexpr int TILE_B = 16;   // grid 256 -> 1 block/CU

// ws layout (bf16 elements)
static constexpr int WALL_OFF = 0;                    // [1152][288] gates(1024) + Wo1ext(128)
static constexpr int W2E_OFF  = 1152 * 288;           // [512][288]  encoder layer2 (+b2 col)
static constexpr int WO2E_OFF = W2E_OFF + 512 * 288;  // [16][128]   Wo2 padded
static constexpr int WS_ELEMS = WO2E_OFF + 16 * 128;

// ---------------- prep: pack weights bf16 (ws re-poisoned every launch) ----------------
__global__ __launch_bounds__(256) void prep_kernel(
    const float* __restrict__ W2,  const float* __restrict__ b2,
    const float* __restrict__ Wih, const float* __restrict__ Whh,
    const float* __restrict__ bih, const float* __restrict__ bhh,
    const float* __restrict__ Wo1, const float* __restrict__ bo1,
    const float* __restrict__ Wo2, bf16_t* __restrict__ ws)
{
    int idx = blockIdx.x * 256 + threadIdx.x;
    if (idx < 1152 * 288) {
        int r = idx / 288, k = idx - r * 288;
        float v = 0.f;
        if (r < 1024) {                       // gate rows: i f g o (256 each)
            if (k < 256)       v = Whh[r * 256 + k];
            else if (k < 259)  v = Wih[r * 3 + (k - 256)];
            else if (k == 259) v = bih[r] + bhh[r];
        } else {                              // Wo1 rows (zeros at x cols, bo1 at ones col)
            int q = r - 1024;
            if (k < 256)       v = Wo1[q * 256 + k];
            else if (k == 259) v = bo1[q];
        }
        ws[WALL_OFF + idx] = (bf16_t)v;
    } else if (idx < W2E_OFF + 512 * 288) {
        int j = idx - W2E_OFF;
        int u = j / 288, k = j - u * 288;
        float v = 0.f;
        if (k < 256)       v = W2[u * 256 + k];
        else if (k == 259) v = b2[u];
        ws[idx] = (bf16_t)v;
    } else if (idx < WS_ELEMS) {
        int j = idx - WO2E_OFF;
        int d = j >> 7, q = j & 127;
        ws[idx] = (bf16_t)((d < 3) ? Wo2[d * 128 + q] : 0.f);
    }
}

// v_rcp_f32 (1 ulp): validated R8/R9 — absmax unchanged (4.88e-4).
__device__ __forceinline__ float rcp_f(float x) {
    float r; asm("v_rcp_f32 %0, %1" : "=v"(r) : "v"(x)); return r;
}
__device__ __forceinline__ float sigm(float x) { return rcp_f(1.f + __expf(-x)); }
// No clamp needed with the rcp form: x->+inf -> 1, x->-inf -> -1, both exact.
__device__ __forceinline__ float tanh_f(float x) {
    float e = __expf(2.f * x);
    return 1.f - 2.f * rcp_f(e + 1.f);   // == (e-1)/(e+1)
}
__device__ __forceinline__ unsigned pk2(float a, float b) {
    union { bf16_t h[2]; unsigned u; } x;
    x.h[0] = (bf16_t)a; x.h[1] = (bf16_t)b; return x.u;
}

// Raw barrier: LDS visibility only (lgkmcnt drain), NO vmcnt drain -> global prefetches
// survive barriers (R7's key fix; __syncthreads' vmcnt(0) drain killed every prefetch).
__device__ __forceinline__ void bar_lds() {
    asm volatile("s_waitcnt lgkmcnt(0)" ::: "memory");
    __builtin_amdgcn_s_barrier();
}

// ---------------- main: 256 blocks x 512 thr (8 waves); block owns 16 batches.
// R13 base (632 us) + G-INTERNAL 1-deep LDS pipeline. Register-lifetime discipline
// (R12's lesson, R13-validated): ONLY transient registers whose live range stays inside
// one phase are allowed; nothing new crosses a barrier or the Y->G back edge.
//   G  : bfn/agn0/agn1 1-ahead pipeline, entry reads AT G START (not carried from Y);
//        +12 regs live kk=0..8 only -- dead before the cell+wrf window (the other peak).
//        Replaces 8 partially-exposed per-kk LDS waits with one entry wait.
//   Z  : zb[3] rolling distance-3 (12 transient regs, B1->B2 only).
//   Y  : batched 8 LDS reads (32 transient regs, B2->loop-end only).
//   o  : same-slot consume-then-refill distance-3 carried ring (24 regs, permanent).
//   Wo1: full wrf[9] burst mid-cell (36 regs, cell->Z only). i,f: af 144 permanent.
// Canary: FETCH_SIZE ~1.47e4 KB. >=1e5 = remat -> revert.
__global__ __launch_bounds__(512, 2) void lstm_main(
    const float* __restrict__ meta, const float* __restrict__ W1,
    const float* __restrict__ b1,   const float* __restrict__ bo2,
    const bf16_t* __restrict__ ws,  float* __restrict__ out)
{
    __shared__ __align__(16) bf16_t hx[2][TILE_B][HS];  // h buffers; ext cols [0,0,0,1,pad]
    __shared__ __align__(16) bf16_t wg[256][GS];        // gate g weights; aliased as cbuf in setup
    __shared__ __align__(16) bf16_t wo2l[16][136];
    __shared__ __align__(16) bf16_t zbuf[TILE_B][136];

    const int tid  = threadIdx.x;
    const int wv   = tid >> 6;       // 0..7
    const int lane = tid & 63;
    const int l15  = lane & 15;
    const int quad = lane >> 4;      // 0..3
    const int gb   = blockIdx.x * TILE_B;

    const bf16_t* wall = ws + WALL_OFF;
    const bf16_t* w2e  = ws + W2E_OFF;
    const bf16_t* wo2e = ws + WO2E_OFF;
    const f32x4 zero4 = {0.f, 0.f, 0.f, 0.f};

    // ---- init ext cols of both hx buffers: zeros, ones col (z-bias via Wo1ext) ----
    if (tid < 32) {
        int buf = tid >> 4, b = tid & 15;
        for (int c2 = 256; c2 < HS; ++c2)
            hx[buf][b][c2] = (bf16_t)((c2 == 259) ? 1.f : 0.f);
    }
    // ---- enc1 (VALU, K=7) into hx[1] ----
    {
        int b = tid & 15, j0 = (tid >> 4) * 8;
        float m[7];
        #pragma unroll
        for (int k = 0; k < 7; ++k) m[k] = meta[(size_t)(gb + b) * 7 + k];
        #pragma unroll
        for (int jj = 0; jj < 8; ++jj) {
            int jd = j0 + jj;
            float acc = b1[jd];
            #pragma unroll
            for (int k = 0; k < 7; ++k) acc += W1[jd * 7 + k] * m[k];
            hx[1][b][jd] = (bf16_t)fmaxf(acc, 0.f);
        }
    }
    __syncthreads();

    // ---- enc2 via MFMA: wave wv rows [64wv,64wv+64); rows<256 -> h0(hx[0]), >=256 -> c0(cbuf) ----
    float* cbuf = (float*)&wg[0][0];  // fp32 [256][17] staging inside wg space
    {
        f32x4 e[4] = {zero4, zero4, zero4, zero4};
        #pragma unroll
        for (int kk = 0; kk < 9; ++kk) {
            int ko = 32 * kk + 8 * quad;
            bf16x8 bf = *(const bf16x8*)&hx[1][l15][ko];
            #pragma unroll
            for (int m = 0; m < 4; ++m) {
                bf16x8 aa = *(const bf16x8*)&w2e[(size_t)(64 * wv + 16 * m + l15) * KEXT + ko];
                e[m] = MFMA16(aa, bf, e[m]);
            }
        }
        #pragma unroll
        for (int m = 0; m < 4; ++m) {
            int row = 64 * wv + 16 * m + 4 * quad;
            if (row < 256) {  // h0
                *(unsigned*)&hx[0][l15][row]     = pk2(fmaxf(e[m][0], 0.f), fmaxf(e[m][1], 0.f));
                *(unsigned*)&hx[0][l15][row + 2] = pk2(fmaxf(e[m][2], 0.f), fmaxf(e[m][3], 0.f));
            } else {          // c0
                int d = row - 256;
                #pragma unroll
                for (int r = 0; r < 4; ++r)
                    cbuf[(size_t)(d + r) * 17 + l15] = fmaxf(e[m][r], 0.f);
            }
        }
    }
    __syncthreads();

    // ---- c0 -> regs: c[half][r] at dim 32wv+16half+4quad+r, batch l15 ----
    f32x4 c[2];
    #pragma unroll
    for (int half = 0; half < 2; ++half)
        #pragma unroll
        for (int r = 0; r < 4; ++r)
            c[half][r] = cbuf[(size_t)(32 * wv + 16 * half + 4 * quad + r) * 17 + l15];
    __syncthreads();

    // ---- gate g -> LDS (overwrites cbuf); Wo2 -> LDS ----
    #pragma unroll
    for (int i = 0; i < 17; ++i) {
        int idx = tid + 512 * i;
        if (idx < 256 * 33) {
            int r = idx / 33, c8 = idx - r * 33;
            *(bf16x8*)&wg[r][8 * c8] = *(const bf16x8*)&wall[(size_t)(512 + r) * KEXT + 8 * c8];
        }
    }
    #pragma unroll
    for (int i = 0; i < 4; ++i) {
        int idx = tid + 512 * i;
        int r = idx >> 7, cc = idx & 127;
        wo2l[r][cc] = wo2e[r * 128 + cc];
    }

    // ---- resident A-frags: gates i,f for dims [32wv,32wv+32): af[g][half][kk] = 144 VGPR ----
    bf16x8 af[2][2][9];
    #pragma unroll
    for (int g = 0; g < 2; ++g)
        #pragma unroll
        for (int h = 0; h < 2; ++h)
            #pragma unroll
            for (int kk = 0; kk < 9; ++kk)
                af[g][h][kk] = *(const bf16x8*)&wall[(size_t)(256 * g + 32 * wv + 16 * h + l15) * KEXT
                                                     + 32 * kk + 8 * quad];

    // ---- stream bases (t-invariant addresses) ----
    const bf16_t* obase = wall + (size_t)(768  + 32 * wv + l15) * KEXT + 8 * quad;  // gate o
    const bf16_t* wbase = wall + (size_t)(1024 + 16 * wv + l15) * KEXT + 8 * quad;  // Wo1

    const float bo2v0 = bo2[0], bo2v1 = bo2[1], bo2v2 = bo2[2];

    // ---- ob ring (carried): prefill slices 0,1,2 -> slots 0,1,2 ----
    bf16x8 ob[3][2];
    #pragma unroll
    for (int s = 0; s < 3; ++s)
        #pragma unroll
        for (int h = 0; h < 2; ++h)
            ob[s][h] = *(const bf16x8*)(obase + (size_t)(16 * h) * KEXT + 32 * s);

    // ---- x_0 fragment in regs: quad0 = {m0,m1,m2,1,0..}, quads 1..3 = 0 ----
    bf16x8 xf;
    #pragma unroll
    for (int j = 0; j < 8; ++j) xf[j] = (bf16_t)0.f;
    if (quad == 0) {
        xf[0] = (bf16_t)meta[(size_t)(gb + l15) * 7 + 0];
        xf[1] = (bf16_t)meta[(size_t)(gb + l15) * 7 + 1];
        xf[2] = (bf16_t)meta[(size_t)(gb + l15) * 7 + 2];
        xf[3] = (bf16_t)1.f;
    }

    __syncthreads();   // wg/wo2l ready (one-time full sync is fine here)

    // ================= time loop: G (gates+cell+wrf burst) -> B1 -> Z -> B2 -> Y ======
    for (int i = 0; i < TSTEPS; ++i) {
        const bf16_t (*cur)[HS] = hx[i & 1];         // h_i
        bf16_t (*nxt)[HS]       = hx[(i + 1) & 1];   // h_{i+1} destination

        // -- G: gates_i = [h_i|x_i|1] @ Wall^T; kk<8 B from LDS, kk=8 B = xf regs.
        //       1-deep in-G pipeline: slice kk+1's 3 ds_reads issue before slice kk's
        //       MFMAs (entry reads at G start; +12 regs live inside G only).
        //       ob: same-slot consume-then-refill distance-3. --
        f32x4 acc[4][2];
        #pragma unroll
        for (int g = 0; g < 4; ++g) { acc[g][0] = zero4; acc[g][1] = zero4; }

        bf16x8 bfn, agn0, agn1;
        bfn  = *(const bf16x8*)&cur[l15][8 * quad];
        agn0 = *(const bf16x8*)&wg[32 * wv + l15][8 * quad];
        agn1 = *(const bf16x8*)&wg[32 * wv + 16 + l15][8 * quad];

        #pragma unroll
        for (int kk = 0; kk < 9; ++kk) {
            bf16x8 bfc = (kk < 8) ? bfn : xf;
            bf16x8 ag0 = agn0, ag1 = agn1;
            if (kk < 8) {
                int ko1 = 32 * (kk + 1) + 8 * quad;
                if (kk + 1 < 8)
                    bfn = *(const bf16x8*)&cur[l15][ko1];
                // kk+1==8: wg read past col 263 aliases next row's cols; B zero there -> harmless
                agn0 = *(const bf16x8*)&wg[32 * wv + l15][ko1];
                agn1 = *(const bf16x8*)&wg[32 * wv + 16 + l15][ko1];
            }
            #pragma unroll
            for (int h = 0; h < 2; ++h) {
                acc[0][h] = MFMA16(af[0][h][kk], bfc, acc[0][h]);
                acc[1][h] = MFMA16(af[1][h][kk], bfc, acc[1][h]);
                acc[2][h] = MFMA16(h ? ag1 : ag0, bfc, acc[2][h]);
                acc[3][h] = MFMA16(ob[kk % 3][h], bfc, acc[3][h]);
            }
            // refill consumed ob slot (WAR orders the load after the MFMA reads;
            // kk=6,7,8 load next-t slices 0,1,2 -> cross-barrier slack)
            #pragma unroll
            for (int h = 0; h < 2; ++h)
                ob[kk % 3][h] = *(const bf16x8*)(obase + (size_t)(16 * h) * KEXT
                                                 + 32 * ((kk + 3) % 9));
        }

        // -- cell update (regs) + write h_{i+1}; wrf burst issued mid-cell (acc dying,
        //    loads get cell+barrier+Z-ramp of slack before first consume) --
        bf16x8 wrf[9];
        {
            // half 0
            float hh[4];
            #pragma unroll
            for (int r = 0; r < 4; ++r) {
                float iv = acc[0][0][r], fv = acc[1][0][r];
                float gv = acc[2][0][r], ov = acc[3][0][r];
                float cc = sigm(fv) * c[0][r] + sigm(iv) * tanh_f(gv);
                c[0][r] = cc;
                hh[r] = sigm(ov) * tanh_f(cc);
            }
            int dim = 32 * wv + 4 * quad;
            *(unsigned*)&nxt[l15][dim]     = pk2(hh[0], hh[1]);
            *(unsigned*)&nxt[l15][dim + 2] = pk2(hh[2], hh[3]);
        }
        #pragma unroll
        for (int s = 0; s < 5; ++s) wrf[s] = *(const bf16x8*)(wbase + 32 * s);
        {
            // half 1
            float hh[4];
            #pragma unroll
            for (int r = 0; r < 4; ++r) {
                float iv = acc[0][1][r], fv = acc[1][1][r];
                float gv = acc[2][1][r], ov = acc[3][1][r];
                float cc = sigm(fv) * c[1][r] + sigm(iv) * tanh_f(gv);
                c[1][r] = cc;
                hh[r] = sigm(ov) * tanh_f(cc);
            }
            int dim = 32 * wv + 16 + 4 * quad;
            *(unsigned*)&nxt[l15][dim]     = pk2(hh[0], hh[1]);
            *(unsigned*)&nxt[l15][dim + 2] = pk2(hh[2], hh[3]);
        }
        #pragma unroll
        for (int s = 5; s < 9; ++s) wrf[s] = *(const bf16x8*)(wbase + 32 * s);
        bar_lds();   // B1: h_{i+1} visible; wrf/ob loads stay in flight

        // -- Z: z_i = relu(h_{i+1} @ Wo1ext^T); wave wv -> z-dims [16wv,16wv+16).
        //       Wo1 from wrf (NO global loads); zb[3] rolling same-slot distance-3
        //       (12 TRANSIENT regs, live B1->B2 only); za 2 parallel chains --
        {
            bf16x8 zb[3];
            #pragma unroll
            for (int s = 0; s < 3; ++s)
                zb[s] = *(const bf16x8*)&nxt[l15][32 * s + 8 * quad];
            f32x4 za0 = zero4, za1 = zero4;
            #pragma unroll
            for (int kk = 0; kk < 9; ++kk) {
                if (kk & 1) za1 = MFMA16(wrf[kk], zb[kk % 3], za1);
                else        za0 = MFMA16(wrf[kk], zb[kk % 3], za0);
                if (kk + 3 <= 8)
                    zb[kk % 3] = *(const bf16x8*)&nxt[l15][32 * (kk + 3) + 8 * quad];
            }
            f32x4 za = za0 + za1;
            int zd = 16 * wv + 4 * quad;
            *(unsigned*)&zbuf[l15][zd]     = pk2(fmaxf(za[0], 0.f), fmaxf(za[1], 0.f));
            *(unsigned*)&zbuf[l15][zd + 2] = pk2(fmaxf(za[2], 0.f), fmaxf(za[3], 0.f));
        }
        bar_lds();   // B2: z complete

        // -- Y: ALL waves redundantly y_i = z @ Wo2ext^T (batched reads, 2 chains;
        //       32 TRANSIENT regs, live B2->loop-end only); xf <- x_{i+1}; rotate
        //       out-store. No trailing barrier; NO next-G prefetch (R12's remat cause). --
        {
            bf16x8 w2b[4], zbb[4];
            #pragma unroll
            for (int kk = 0; kk < 4; ++kk) {
                int ko = 32 * kk + 8 * quad;
                w2b[kk] = *(const bf16x8*)&wo2l[l15][ko];
                zbb[kk] = *(const bf16x8*)&zbuf[l15][ko];
            }
            f32x4 ya0 = zero4, ya1 = zero4;
            #pragma unroll
            for (int kk = 0; kk < 4; ++kk) {
                if (kk & 2) ya1 = MFMA16(w2b[kk], zbb[kk], ya1);
                else        ya0 = MFMA16(w2b[kk], zbb[kk], ya0);
            }
            f32x4 yv = ya0 + ya1;
            float y0 = yv[0] + bo2v0, y1 = yv[1] + bo2v1, y2 = yv[2] + bo2v2;
            if (wv == (i & 7) && quad == 0) {   // rotate storer: ack never blocks a barrier
                float* op = out + ((size_t)(gb + l15) * TSTEPS + i) * 3;
                op[0] = y0; op[1] = y1; op[2] = y2;
            }
            if (quad == 0) {
                xf[0] = (bf16_t)y0; xf[1] = (bf16_t)y1; xf[2] = (bf16_t)y2; xf[3] = (bf16_t)1.f;
            }
        }
    }
}

extern "C" void kernel_launch(void* const* d_in, const int* in_sizes, int n_in,
                              void* d_out, int out_size, void* d_ws, size_t ws_size,
                              hipStream_t stream)
{
    const float* meta = (const float*)d_in[0];
    const float* W1   = (const float*)d_in[2];
    const float* b1   = (const float*)d_in[3];
    const float* W2   = (const float*)d_in[4];
    const float* b2   = (const float*)d_in[5];
    const float* Wih  = (const float*)d_in[6];
    const float* Whh  = (const float*)d_in[7];
    const float* bih  = (const float*)d_in[8];
    const float* bhh  = (const float*)d_in[9];
    const float* Wo1  = (const float*)d_in[10];
    const float* bo1  = (const float*)d_in[11];
    const float* Wo2  = (const float*)d_in[12];
    const float* bo2  = (const float*)d_in[13];
    bf16_t* ws  = (bf16_t*)d_ws;
    float*  out = (float*)d_out;

    prep_kernel<<<dim3((WS_ELEMS + 255) / 256), dim3(256), 0, stream>>>(
        W2, b2, Wih, Whh, bih, bhh, Wo1, bo1, Wo2, ws);
    lstm_main<<<dim3(4096 / TILE_B), dim3(512), 0, stream>>>(
        meta, W1, b1, bo2, ws, out);
}

// Round 15
// 629.892 us; speedup vs baseline: 1.3190x; 1.3190x over previous
//
#include <hip/hip_runtime.h>

typedef __bf16 bf16_t;
typedef bf16_t bf16x8 __attribute__((ext_vector_type(8)));
typedef float  f32x4  __attribute__((ext_vector_type(4)));

#define MFMA16(A, B, C) __builtin_amdgcn_mfma_f32_16x16x32_bf16((A), (B), (C), 0, 0, 0)

static constexpr int KEXT   = 288;  // 256 h | 3 x | 1 ones(bias) | 28 zero pad
static constexpr int HS     = 296;  // hx LDS row stride
static constexpr int GS     = 264;  // gate-g LDS tile stride
static constexpr int TSTEPS = 128;
static constexpr int TILE_B = 16;   // grid 256 -> 1 block/CU

// ws layout (bf16 elements)
static constexpr int WALL_OFF = 0;                    // [1152][288] gates(1024) + Wo1ext(128)
static constexpr int W2E_OFF  = 1152 * 288;           // [512][288]  encoder layer2 (+b2 col)
static constexpr int WO2E_OFF = W2E_OFF + 512 * 288;  // [16][128]   Wo2 padded
static constexpr int WS_ELEMS = WO2E_OFF + 16 * 128;

// ---------------- prep: pack weights bf16 (ws re-poisoned every launch) ----------------
__global__ __launch_bounds__(256) void prep_kernel(
    const float* __restrict__ W2,  const float* __restrict__ b2,
    const float* __restrict__ Wih, const float* __restrict__ Whh,
    const float* __restrict__ bih, const float* __restrict__ bhh,
    const float* __restrict__ Wo1, const float* __restrict__ bo1,
    const float* __restrict__ Wo2, bf16_t* __restrict__ ws)
{
    int idx = blockIdx.x * 256 + threadIdx.x;
    if (idx < 1152 * 288) {
        int r = idx / 288, k = idx - r * 288;
        float v = 0.f;
        if (r < 1024) {                       // gate rows: i f g o (256 each)
            if (k < 256)       v = Whh[r * 256 + k];
            else if (k < 259)  v = Wih[r * 3 + (k - 256)];
            else if (k == 259) v = bih[r] + bhh[r];
        } else {                              // Wo1 rows (zeros at x cols, bo1 at ones col)
            int q = r - 1024;
            if (k < 256)       v = Wo1[q * 256 + k];
            else if (k == 259) v = bo1[q];
        }
        ws[WALL_OFF + idx] = (bf16_t)v;
    } else if (idx < W2E_OFF + 512 * 288) {
        int j = idx - W2E_OFF;
        int u = j / 288, k = j - u * 288;
        float v = 0.f;
        if (k < 256)       v = W2[u * 256 + k];
        else if (k == 259) v = b2[u];
        ws[idx] = (bf16_t)v;
    } else if (idx < WS_ELEMS) {
        int j = idx - WO2E_OFF;
        int d = j >> 7, q = j & 127;
        ws[idx] = (bf16_t)((d < 3) ? Wo2[d * 128 + q] : 0.f);
    }
}

// v_rcp_f32 (1 ulp): validated R8/R9 — absmax unchanged (4.88e-4).
__device__ __forceinline__ float rcp_f(float x) {
    float r; asm("v_rcp_f32 %0, %1" : "=v"(r) : "v"(x)); return r;
}
__device__ __forceinline__ float sigm(float x) { return rcp_f(1.f + __expf(-x)); }
// No clamp needed with the rcp form: x->+inf -> 1, x->-inf -> -1, both exact.
__device__ __forceinline__ float tanh_f(float x) {
    float e = __expf(2.f * x);
    return 1.f - 2.f * rcp_f(e + 1.f);   // == (e-1)/(e+1)
}
__device__ __forceinline__ unsigned pk2(float a, float b) {
    union { bf16_t h[2]; unsigned u; } x;
    x.h[0] = (bf16_t)a; x.h[1] = (bf16_t)b; return x.u;
}

// Raw barrier: LDS visibility only (lgkmcnt drain), NO vmcnt drain -> global prefetches
// survive barriers (R7's key fix; __syncthreads' vmcnt(0) drain killed every prefetch).
__device__ __forceinline__ void bar_lds() {
    asm volatile("s_waitcnt lgkmcnt(0)" ::: "memory");
    __builtin_amdgcn_s_barrier();
}

// ---------------- main: 256 blocks x 512 thr (8 waves); block owns 16 batches.
// TERMINAL CONFIGURATION (R13, 632 us; 2.22x vs session start). Structure:
//   G (gates+cell+wrf burst) -> B1 -> Z -> B2 -> Y, 2 raw barriers/t.
//   i,f : VGPR-resident af[2][2][9] (144 permanent regs)
//   g   : LDS-resident wg[256][264]
//   o   : same-slot consume-then-refill distance-3 carried ring (24 permanent regs)
//   Wo1 : full wrf[9] burst mid-cell (36 transient regs, cell->Z only)
//   Z   : zb[3] rolling distance-3 (transient); Y: batched reads (transient)
// Measured lessons locked into this shape:
//   * __syncthreads' vmcnt(0) drain kills cross-phase prefetch -> raw lgkmcnt barriers
//   * G has ZERO carried-register headroom: +24 carried regs => af remat from global
//     (R8/R12: FETCH 14.7e3 -> 0.2-2.8e6 KB). Transient-only additions are safe (R13).
//   * Hand-pipelining G's LDS reads loses even without remat (R14: compiler's natural
//     schedule at ~240 regs is the optimum; hoisted reads serialize lgkmcnt waits).
//   * Stream loads must issue in register-slack phases with >=1 phase of slack (R10
//     wrf burst: -27%); phase-start bursts expose loaded-L2 latency (R4: +2x FETCH).
// Remaining gap (11.7k cyc/t vs ~4.8k LDS-pipe floor) is the serial-dependence latency
// equilibrium at 2 waves/SIMD; all structural alternatives measured/computed worse.
__global__ __launch_bounds__(512, 2) void lstm_main(
    const float* __restrict__ meta, const float* __restrict__ W1,
    const float* __restrict__ b1,   const float* __restrict__ bo2,
    const bf16_t* __restrict__ ws,  float* __restrict__ out)
{
    __shared__ __align__(16) bf16_t hx[2][TILE_B][HS];  // h buffers; ext cols [0,0,0,1,pad]
    __shared__ __align__(16) bf16_t wg[256][GS];        // gate g weights; aliased as cbuf in setup
    __shared__ __align__(16) bf16_t wo2l[16][136];
    __shared__ __align__(16) bf16_t zbuf[TILE_B][136];

    const int tid  = threadIdx.x;
    const int wv   = tid >> 6;       // 0..7
    const int lane = tid & 63;
    const int l15  = lane & 15;
    const int quad = lane >> 4;      // 0..3
    const int gb   = blockIdx.x * TILE_B;

    const bf16_t* wall = ws + WALL_OFF;
    const bf16_t* w2e  = ws + W2E_OFF;
    const bf16_t* wo2e = ws + WO2E_OFF;
    const f32x4 zero4 = {0.f, 0.f, 0.f, 0.f};

    // ---- init ext cols of both hx buffers: zeros, ones col (z-bias via Wo1ext) ----
    if (tid < 32) {
        int buf = tid >> 4, b = tid & 15;
        for (int c2 = 256; c2 < HS; ++c2)
            hx[buf][b][c2] = (bf16_t)((c2 == 259) ? 1.f : 0.f);
    }
    // ---- enc1 (VALU, K=7) into hx[1] ----
    {
        int b = tid & 15, j0 = (tid >> 4) * 8;
        float m[7];
        #pragma unroll
        for (int k = 0; k < 7; ++k) m[k] = meta[(size_t)(gb + b) * 7 + k];
        #pragma unroll
        for (int jj = 0; jj < 8; ++jj) {
            int jd = j0 + jj;
            float acc = b1[jd];
            #pragma unroll
            for (int k = 0; k < 7; ++k) acc += W1[jd * 7 + k] * m[k];
            hx[1][b][jd] = (bf16_t)fmaxf(acc, 0.f);
        }
    }
    __syncthreads();

    // ---- enc2 via MFMA: wave wv rows [64wv,64wv+64); rows<256 -> h0(hx[0]), >=256 -> c0(cbuf) ----
    float* cbuf = (float*)&wg[0][0];  // fp32 [256][17] staging inside wg space
    {
        f32x4 e[4] = {zero4, zero4, zero4, zero4};
        #pragma unroll
        for (int kk = 0; kk < 9; ++kk) {
            int ko = 32 * kk + 8 * quad;
            bf16x8 bf = *(const bf16x8*)&hx[1][l15][ko];
            #pragma unroll
            for (int m = 0; m < 4; ++m) {
                bf16x8 aa = *(const bf16x8*)&w2e[(size_t)(64 * wv + 16 * m + l15) * KEXT + ko];
                e[m] = MFMA16(aa, bf, e[m]);
            }
        }
        #pragma unroll
        for (int m = 0; m < 4; ++m) {
            int row = 64 * wv + 16 * m + 4 * quad;
            if (row < 256) {  // h0
                *(unsigned*)&hx[0][l15][row]     = pk2(fmaxf(e[m][0], 0.f), fmaxf(e[m][1], 0.f));
                *(unsigned*)&hx[0][l15][row + 2] = pk2(fmaxf(e[m][2], 0.f), fmaxf(e[m][3], 0.f));
            } else {          // c0
                int d = row - 256;
                #pragma unroll
                for (int r = 0; r < 4; ++r)
                    cbuf[(size_t)(d + r) * 17 + l15] = fmaxf(e[m][r], 0.f);
            }
        }
    }
    __syncthreads();

    // ---- c0 -> regs: c[half][r] at dim 32wv+16half+4quad+r, batch l15 ----
    f32x4 c[2];
    #pragma unroll
    for (int half = 0; half < 2; ++half)
        #pragma unroll
        for (int r = 0; r < 4; ++r)
            c[half][r] = cbuf[(size_t)(32 * wv + 16 * half + 4 * quad + r) * 17 + l15];
    __syncthreads();

    // ---- gate g -> LDS (overwrites cbuf); Wo2 -> LDS ----
    #pragma unroll
    for (int i = 0; i < 17; ++i) {
        int idx = tid + 512 * i;
        if (idx < 256 * 33) {
            int r = idx / 33, c8 = idx - r * 33;
            *(bf16x8*)&wg[r][8 * c8] = *(const bf16x8*)&wall[(size_t)(512 + r) * KEXT + 8 * c8];
        }
    }
    #pragma unroll
    for (int i = 0; i < 4; ++i) {
        int idx = tid + 512 * i;
        int r = idx >> 7, cc = idx & 127;
        wo2l[r][cc] = wo2e[r * 128 + cc];
    }

    // ---- resident A-frags: gates i,f for dims [32wv,32wv+32): af[g][half][kk] = 144 VGPR ----
    bf16x8 af[2][2][9];
    #pragma unroll
    for (int g = 0; g < 2; ++g)
        #pragma unroll
        for (int h = 0; h < 2; ++h)
            #pragma unroll
            for (int kk = 0; kk < 9; ++kk)
                af[g][h][kk] = *(const bf16x8*)&wall[(size_t)(256 * g + 32 * wv + 16 * h + l15) * KEXT
                                                     + 32 * kk + 8 * quad];

    // ---- stream bases (t-invariant addresses) ----
    const bf16_t* obase = wall + (size_t)(768  + 32 * wv + l15) * KEXT + 8 * quad;  // gate o
    const bf16_t* wbase = wall + (size_t)(1024 + 16 * wv + l15) * KEXT + 8 * quad;  // Wo1

    const float bo2v0 = bo2[0], bo2v1 = bo2[1], bo2v2 = bo2[2];

    // ---- ob ring (carried): prefill slices 0,1,2 -> slots 0,1,2 ----
    bf16x8 ob[3][2];
    #pragma unroll
    for (int s = 0; s < 3; ++s)
        #pragma unroll
        for (int h = 0; h < 2; ++h)
            ob[s][h] = *(const bf16x8*)(obase + (size_t)(16 * h) * KEXT + 32 * s);

    // ---- x_0 fragment in regs: quad0 = {m0,m1,m2,1,0..}, quads 1..3 = 0 ----
    bf16x8 xf;
    #pragma unroll
    for (int j = 0; j < 8; ++j) xf[j] = (bf16_t)0.f;
    if (quad == 0) {
        xf[0] = (bf16_t)meta[(size_t)(gb + l15) * 7 + 0];
        xf[1] = (bf16_t)meta[(size_t)(gb + l15) * 7 + 1];
        xf[2] = (bf16_t)meta[(size_t)(gb + l15) * 7 + 2];
        xf[3] = (bf16_t)1.f;
    }

    __syncthreads();   // wg/wo2l ready (one-time full sync is fine here)

    // ================= time loop: G (gates+cell+wrf burst) -> B1 -> Z -> B2 -> Y ======
    for (int i = 0; i < TSTEPS; ++i) {
        const bf16_t (*cur)[HS] = hx[i & 1];         // h_i
        bf16_t (*nxt)[HS]       = hx[(i + 1) & 1];   // h_{i+1} destination

        // -- G (compiler-scheduled; do NOT hand-pipeline -- R14): gates_i = [h_i|x_i|1]
        //       @ Wall^T; kk<8 B from LDS, kk=8 B = xf regs.
        //       ob: same-slot consume-then-refill distance-3. --
        f32x4 acc[4][2];
        #pragma unroll
        for (int g = 0; g < 4; ++g) { acc[g][0] = zero4; acc[g][1] = zero4; }

        #pragma unroll
        for (int kk = 0; kk < 9; ++kk) {
            int ko = 32 * kk + 8 * quad;
            bf16x8 bf = (kk < 8) ? *(const bf16x8*)&cur[l15][ko] : xf;
            #pragma unroll
            for (int h = 0; h < 2; ++h) {
                // kk=8: wg read past col 263 aliases next row's cols; B is zero there -> harmless
                bf16x8 ag = *(const bf16x8*)&wg[32 * wv + 16 * h + l15][ko];
                acc[0][h] = MFMA16(af[0][h][kk], bf, acc[0][h]);
                acc[1][h] = MFMA16(af[1][h][kk], bf, acc[1][h]);
                acc[2][h] = MFMA16(ag,            bf, acc[2][h]);
                acc[3][h] = MFMA16(ob[kk % 3][h], bf, acc[3][h]);
            }
            // refill consumed slot (WAR orders the load after the MFMA reads;
            // kk=6,7,8 load next-t slices 0,1,2 -> cross-barrier slack)
            #pragma unroll
            for (int h = 0; h < 2; ++h)
                ob[kk % 3][h] = *(const bf16x8*)(obase + (size_t)(16 * h) * KEXT
                                                 + 32 * ((kk + 3) % 9));
        }

        // -- cell update (regs) + write h_{i+1}; wrf burst issued mid-cell (acc dying,
        //    loads get cell+barrier+Z-ramp of slack before first consume) --
        bf16x8 wrf[9];
        {
            // half 0
            float hh[4];
            #pragma unroll
            for (int r = 0; r < 4; ++r) {
                float iv = acc[0][0][r], fv = acc[1][0][r];
                float gv = acc[2][0][r], ov = acc[3][0][r];
                float cc = sigm(fv) * c[0][r] + sigm(iv) * tanh_f(gv);
                c[0][r] = cc;
                hh[r] = sigm(ov) * tanh_f(cc);
            }
            int dim = 32 * wv + 4 * quad;
            *(unsigned*)&nxt[l15][dim]     = pk2(hh[0], hh[1]);
            *(unsigned*)&nxt[l15][dim + 2] = pk2(hh[2], hh[3]);
        }
        #pragma unroll
        for (int s = 0; s < 5; ++s) wrf[s] = *(const bf16x8*)(wbase + 32 * s);
        {
            // half 1
            float hh[4];
            #pragma unroll
            for (int r = 0; r < 4; ++r) {
                float iv = acc[0][1][r], fv = acc[1][1][r];
                float gv = acc[2][1][r], ov = acc[3][1][r];
                float cc = sigm(fv) * c[1][r] + sigm(iv) * tanh_f(gv);
                c[1][r] = cc;
                hh[r] = sigm(ov) * tanh_f(cc);
            }
            int dim = 32 * wv + 16 + 4 * quad;
            *(unsigned*)&nxt[l15][dim]     = pk2(hh[0], hh[1]);
            *(unsigned*)&nxt[l15][dim + 2] = pk2(hh[2], hh[3]);
        }
        #pragma unroll
        for (int s = 5; s < 9; ++s) wrf[s] = *(const bf16x8*)(wbase + 32 * s);
        bar_lds();   // B1: h_{i+1} visible; wrf/ob loads stay in flight

        // -- Z: z_i = relu(h_{i+1} @ Wo1ext^T); wave wv -> z-dims [16wv,16wv+16).
        //       Wo1 from wrf (NO global loads); zb[3] rolling same-slot distance-3
        //       (12 TRANSIENT regs, live B1->B2 only); za 2 parallel chains --
        {
            bf16x8 zb[3];
            #pragma unroll
            for (int s = 0; s < 3; ++s)
                zb[s] = *(const bf16x8*)&nxt[l15][32 * s + 8 * quad];
            f32x4 za0 = zero4, za1 = zero4;
            #pragma unroll
            for (int kk = 0; kk < 9; ++kk) {
                if (kk & 1) za1 = MFMA16(wrf[kk], zb[kk % 3], za1);
                else        za0 = MFMA16(wrf[kk], zb[kk % 3], za0);
                if (kk + 3 <= 8)
                    zb[kk % 3] = *(const bf16x8*)&nxt[l15][32 * (kk + 3) + 8 * quad];
            }
            f32x4 za = za0 + za1;
            int zd = 16 * wv + 4 * quad;
            *(unsigned*)&zbuf[l15][zd]     = pk2(fmaxf(za[0], 0.f), fmaxf(za[1], 0.f));
            *(unsigned*)&zbuf[l15][zd + 2] = pk2(fmaxf(za[2], 0.f), fmaxf(za[3], 0.f));
        }
        bar_lds();   // B2: z complete

        // -- Y: ALL waves redundantly y_i = z @ Wo2ext^T (batched reads, 2 chains;
        //       32 TRANSIENT regs, live B2->loop-end only); xf <- x_{i+1}; rotate
        //       out-store. No trailing barrier; NO next-G prefetch (R12's remat cause). --
        {
            bf16x8 w2b[4], zbb[4];
            #pragma unroll
            for (int kk = 0; kk < 4; ++kk) {
                int ko = 32 * kk + 8 * quad;
                w2b[kk] = *(const bf16x8*)&wo2l[l15][ko];
                zbb[kk] = *(const bf16x8*)&zbuf[l15][ko];
            }
            f32x4 ya0 = zero4, ya1 = zero4;
            #pragma unroll
            for (int kk = 0; kk < 4; ++kk) {
                if (kk & 2) ya1 = MFMA16(w2b[kk], zbb[kk], ya1);
                else        ya0 = MFMA16(w2b[kk], zbb[kk], ya0);
            }
            f32x4 yv = ya0 + ya1;
            float y0 = yv[0] + bo2v0, y1 = yv[1] + bo2v1, y2 = yv[2] + bo2v2;
            if (wv == (i & 7) && quad == 0) {   // rotate storer: ack never blocks a barrier
                float* op = out + ((size_t)(gb + l15) * TSTEPS + i) * 3;
                op[0] = y0; op[1] = y1; op[2] = y2;
            }
            if (quad == 0) {
                xf[0] = (bf16_t)y0; xf[1] = (bf16_t)y1; xf[2] = (bf16_t)y2; xf[3] = (bf16_t)1.f;
            }
        }
    }
}

extern "C" void kernel_launch(void* const* d_in, const int* in_sizes, int n_in,
                              void* d_out, int out_size, void* d_ws, size_t ws_size,
                              hipStream_t stream)
{
    const float* meta = (const float*)d_in[0];
    const float* W1   = (const float*)d_in[2];
    const float* b1   = (const float*)d_in[3];
    const float* W2   = (const float*)d_in[4];
    const float* b2   = (const float*)d_in[5];
    const float* Wih  = (const float*)d_in[6];
    const float* Whh  = (const float*)d_in[7];
    const float* bih  = (const float*)d_in[8];
    const float* bhh  = (const float*)d_in[9];
    const float* Wo1  = (const float*)d_in[10];
    const float* bo1  = (const float*)d_in[11];
    const float* Wo2  = (const float*)d_in[12];
    const float* bo2  = (const float*)d_in[13];
    bf16_t* ws  = (bf16_t*)d_ws;
    float*  out = (float*)d_out;

    prep_kernel<<<dim3((WS_ELEMS + 255) / 256), dim3(256), 0, stream>>>(
        W2, b2, Wih, Whh, bih, bhh, Wo1, bo1, Wo2, ws);
    lstm_main<<<dim3(4096 / TILE_B), dim3(512), 0, stream>>>(
        meta, W1, b1, bo2, ws, out);
}

// Round 16
// 616.816 us; speedup vs baseline: 1.3469x; 1.0212x over previous
//
#include <hip/hip_runtime.h>

typedef __bf16 bf16_t;
typedef bf16_t bf16x8 __attribute__((ext_vector_type(8)));
typedef float  f32x4  __attribute__((ext_vector_type(4)));

#define MFMA16(A, B, C) __builtin_amdgcn_mfma_f32_16x16x32_bf16((A), (B), (C), 0, 0, 0)

static constexpr int KEXT   = 288;  // 256 h | 3 x | 1 ones(bias) | 28 zero pad
static constexpr int HS     = 296;  // hx LDS row stride
static constexpr int GS     = 264;  // gate-g LDS tile stride
static constexpr int TSTEPS = 128;
static constexpr int TILE_B = 16;   // grid 256 -> 1 block/CU

// ws layout (bf16 elements)
static constexpr int WALL_OFF = 0;                    // [1152][288] gates(1024) + Wo1ext(128)
static constexpr int W2E_OFF  = 1152 * 288;           // [512][288]  encoder layer2 (+b2 col)
static constexpr int WO2E_OFF = W2E_OFF + 512 * 288;  // [16][128]   Wo2 padded
static constexpr int WS_ELEMS = WO2E_OFF + 16 * 128;

// ---------------- prep: pack weights bf16 (ws re-poisoned every launch) ----------------
__global__ __launch_bounds__(256) void prep_kernel(
    const float* __restrict__ W2,  const float* __restrict__ b2,
    const float* __restrict__ Wih, const float* __restrict__ Whh,
    const float* __restrict__ bih, const float* __restrict__ bhh,
    const float* __restrict__ Wo1, const float* __restrict__ bo1,
    const float* __restrict__ Wo2, bf16_t* __restrict__ ws)
{
    int idx = blockIdx.x * 256 + threadIdx.x;
    if (idx < 1152 * 288) {
        int r = idx / 288, k = idx - r * 288;
        float v = 0.f;
        if (r < 1024) {                       // gate rows: i f g o (256 each)
            if (k < 256)       v = Whh[r * 256 + k];
            else if (k < 259)  v = Wih[r * 3 + (k - 256)];
            else if (k == 259) v = bih[r] + bhh[r];
        } else {                              // Wo1 rows (zeros at x cols, bo1 at ones col)
            int q = r - 1024;
            if (k < 256)       v = Wo1[q * 256 + k];
            else if (k == 259) v = bo1[q];
        }
        ws[WALL_OFF + idx] = (bf16_t)v;
    } else if (idx < W2E_OFF + 512 * 288) {
        int j = idx - W2E_OFF;
        int u = j / 288, k = j - u * 288;
        float v = 0.f;
        if (k < 256)       v = W2[u * 256 + k];
        else if (k == 259) v = b2[u];
        ws[idx] = (bf16_t)v;
    } else if (idx < WS_ELEMS) {
        int j = idx - WO2E_OFF;
        int d = j >> 7, q = j & 127;
        ws[idx] = (bf16_t)((d < 3) ? Wo2[d * 128 + q] : 0.f);
    }
}

// v_rcp_f32 (1 ulp): validated R8/R9 — absmax unchanged (4.88e-4).
__device__ __forceinline__ float rcp_f(float x) {
    float r; asm("v_rcp_f32 %0, %1" : "=v"(r) : "v"(x)); return r;
}
__device__ __forceinline__ float sigm(float x) { return rcp_f(1.f + __expf(-x)); }
// No clamp needed with the rcp form: x->+inf -> 1, x->-inf -> -1, both exact.
__device__ __forceinline__ float tanh_f(float x) {
    float e = __expf(2.f * x);
    return 1.f - 2.f * rcp_f(e + 1.f);   // == (e-1)/(e+1)
}
__device__ __forceinline__ unsigned pk2(float a, float b) {
    union { bf16_t h[2]; unsigned u; } x;
    x.h[0] = (bf16_t)a; x.h[1] = (bf16_t)b; return x.u;
}

// Raw barrier: LDS visibility only (lgkmcnt drain), NO vmcnt drain -> global prefetches
// survive barriers (R7's key fix; __syncthreads' vmcnt(0) drain killed every prefetch).
__device__ __forceinline__ void bar_lds() {
    asm volatile("s_waitcnt lgkmcnt(0)" ::: "memory");
    __builtin_amdgcn_s_barrier();
}

// ---------------- main: 256 blocks x 512 thr (8 waves); block owns 16 batches.
// R13 components with the loop ROTATED so Y_i and G_{i+1} kk0..7 share one straight-line
// region (R13's loop back-edge was a compiler scheduling fence that kept Y's ~400-cyc
// serial tail on the critical path; the 64 independent G MFMAs can absorb it):
//   prologue: G_0 + cell -> h_1 + wrf burst -> B1
//   iter i  : Z_i -> B2 -> { G_{i+1} kk0..7 ; Y_i (xf<-x_{i+1}) ; kk8 } -> cell -> wrf -> B1
// Liveness (R8/R12 discipline): acc born post-B2, dies pre-B1 (no barrier crossed);
// wrf dead during G kk0..7 (consumed by Z_i), reborn mid-cell; Y transients coexist
// with acc but hoisting is compiler-optional (graceful, not forced remat).
// Weight placement unchanged: i,f af[2][2][9] (144 regs); g LDS wg; o same-slot
// distance-3 carried ring; Wo1 wrf[9] mid-cell burst. 2 raw barriers/t.
// Canary: FETCH_SIZE ~1.5e4 KB; >=1e5 = remat -> revert to R15 (630 us, verified).
__global__ __launch_bounds__(512, 2) void lstm_main(
    const float* __restrict__ meta, const float* __restrict__ W1,
    const float* __restrict__ b1,   const float* __restrict__ bo2,
    const bf16_t* __restrict__ ws,  float* __restrict__ out)
{
    __shared__ __align__(16) bf16_t hx[2][TILE_B][HS];  // h buffers; ext cols [0,0,0,1,pad]
    __shared__ __align__(16) bf16_t wg[256][GS];        // gate g weights; aliased as cbuf in setup
    __shared__ __align__(16) bf16_t wo2l[16][136];
    __shared__ __align__(16) bf16_t zbuf[TILE_B][136];

    const int tid  = threadIdx.x;
    const int wv   = tid >> 6;       // 0..7
    const int lane = tid & 63;
    const int l15  = lane & 15;
    const int quad = lane >> 4;      // 0..3
    const int gb   = blockIdx.x * TILE_B;

    const bf16_t* wall = ws + WALL_OFF;
    const bf16_t* w2e  = ws + W2E_OFF;
    const bf16_t* wo2e = ws + WO2E_OFF;
    const f32x4 zero4 = {0.f, 0.f, 0.f, 0.f};

    // ---- init ext cols of both hx buffers: zeros, ones col (z-bias via Wo1ext) ----
    if (tid < 32) {
        int buf = tid >> 4, b = tid & 15;
        for (int c2 = 256; c2 < HS; ++c2)
            hx[buf][b][c2] = (bf16_t)((c2 == 259) ? 1.f : 0.f);
    }
    // ---- enc1 (VALU, K=7) into hx[1] ----
    {
        int b = tid & 15, j0 = (tid >> 4) * 8;
        float m[7];
        #pragma unroll
        for (int k = 0; k < 7; ++k) m[k] = meta[(size_t)(gb + b) * 7 + k];
        #pragma unroll
        for (int jj = 0; jj < 8; ++jj) {
            int jd = j0 + jj;
            float acc = b1[jd];
            #pragma unroll
            for (int k = 0; k < 7; ++k) acc += W1[jd * 7 + k] * m[k];
            hx[1][b][jd] = (bf16_t)fmaxf(acc, 0.f);
        }
    }
    __syncthreads();

    // ---- enc2 via MFMA: wave wv rows [64wv,64wv+64); rows<256 -> h0(hx[0]), >=256 -> c0(cbuf) ----
    float* cbuf = (float*)&wg[0][0];  // fp32 [256][17] staging inside wg space
    {
        f32x4 e[4] = {zero4, zero4, zero4, zero4};
        #pragma unroll
        for (int kk = 0; kk < 9; ++kk) {
            int ko = 32 * kk + 8 * quad;
            bf16x8 bf = *(const bf16x8*)&hx[1][l15][ko];
            #pragma unroll
            for (int m = 0; m < 4; ++m) {
                bf16x8 aa = *(const bf16x8*)&w2e[(size_t)(64 * wv + 16 * m + l15) * KEXT + ko];
                e[m] = MFMA16(aa, bf, e[m]);
            }
        }
        #pragma unroll
        for (int m = 0; m < 4; ++m) {
            int row = 64 * wv + 16 * m + 4 * quad;
            if (row < 256) {  // h0
                *(unsigned*)&hx[0][l15][row]     = pk2(fmaxf(e[m][0], 0.f), fmaxf(e[m][1], 0.f));
                *(unsigned*)&hx[0][l15][row + 2] = pk2(fmaxf(e[m][2], 0.f), fmaxf(e[m][3], 0.f));
            } else {          // c0
                int d = row - 256;
                #pragma unroll
                for (int r = 0; r < 4; ++r)
                    cbuf[(size_t)(d + r) * 17 + l15] = fmaxf(e[m][r], 0.f);
            }
        }
    }
    __syncthreads();

    // ---- c0 -> regs: c[half][r] at dim 32wv+16half+4quad+r, batch l15 ----
    f32x4 c[2];
    #pragma unroll
    for (int half = 0; half < 2; ++half)
        #pragma unroll
        for (int r = 0; r < 4; ++r)
            c[half][r] = cbuf[(size_t)(32 * wv + 16 * half + 4 * quad + r) * 17 + l15];
    __syncthreads();

    // ---- gate g -> LDS (overwrites cbuf); Wo2 -> LDS ----
    #pragma unroll
    for (int i = 0; i < 17; ++i) {
        int idx = tid + 512 * i;
        if (idx < 256 * 33) {
            int r = idx / 33, c8 = idx - r * 33;
            *(bf16x8*)&wg[r][8 * c8] = *(const bf16x8*)&wall[(size_t)(512 + r) * KEXT + 8 * c8];
        }
    }
    #pragma unroll
    for (int i = 0; i < 4; ++i) {
        int idx = tid + 512 * i;
        int r = idx >> 7, cc = idx & 127;
        wo2l[r][cc] = wo2e[r * 128 + cc];
    }

    // ---- resident A-frags: gates i,f for dims [32wv,32wv+32): af[g][half][kk] = 144 VGPR ----
    bf16x8 af[2][2][9];
    #pragma unroll
    for (int g = 0; g < 2; ++g)
        #pragma unroll
        for (int h = 0; h < 2; ++h)
            #pragma unroll
            for (int kk = 0; kk < 9; ++kk)
                af[g][h][kk] = *(const bf16x8*)&wall[(size_t)(256 * g + 32 * wv + 16 * h + l15) * KEXT
                                                     + 32 * kk + 8 * quad];

    // ---- stream bases (t-invariant addresses) ----
    const bf16_t* obase = wall + (size_t)(768  + 32 * wv + l15) * KEXT + 8 * quad;  // gate o
    const bf16_t* wbase = wall + (size_t)(1024 + 16 * wv + l15) * KEXT + 8 * quad;  // Wo1

    const float bo2v0 = bo2[0], bo2v1 = bo2[1], bo2v2 = bo2[2];

    // ---- ob ring (carried): prefill slices 0,1,2 -> slots 0,1,2 ----
    bf16x8 ob[3][2];
    #pragma unroll
    for (int s = 0; s < 3; ++s)
        #pragma unroll
        for (int h = 0; h < 2; ++h)
            ob[s][h] = *(const bf16x8*)(obase + (size_t)(16 * h) * KEXT + 32 * s);

    // ---- x_0 fragment in regs: quad0 = {m0,m1,m2,1,0..}, quads 1..3 = 0 ----
    bf16x8 xf;
    #pragma unroll
    for (int j = 0; j < 8; ++j) xf[j] = (bf16_t)0.f;
    if (quad == 0) {
        xf[0] = (bf16_t)meta[(size_t)(gb + l15) * 7 + 0];
        xf[1] = (bf16_t)meta[(size_t)(gb + l15) * 7 + 1];
        xf[2] = (bf16_t)meta[(size_t)(gb + l15) * 7 + 2];
        xf[3] = (bf16_t)1.f;
    }

    // wrf carried across the back edge: loaded mid-cell, consumed by next Z
    bf16x8 wrf[9];

    __syncthreads();   // wg/wo2l ready (one-time full sync is fine here)

    // ---- prologue: G_0 (gates from h_0 + x_0, ob ring), cell -> h_1, wrf burst ----
    {
        f32x4 acc[4][2];
        #pragma unroll
        for (int g = 0; g < 4; ++g) { acc[g][0] = zero4; acc[g][1] = zero4; }

        #pragma unroll
        for (int kk = 0; kk < 9; ++kk) {
            int ko = 32 * kk + 8 * quad;
            bf16x8 bf = (kk < 8) ? *(const bf16x8*)&hx[0][l15][ko] : xf;
            #pragma unroll
            for (int h = 0; h < 2; ++h) {
                // kk=8: wg read past col 263 aliases next row's cols; B zero there -> harmless
                bf16x8 ag = *(const bf16x8*)&wg[32 * wv + 16 * h + l15][ko];
                acc[0][h] = MFMA16(af[0][h][kk], bf, acc[0][h]);
                acc[1][h] = MFMA16(af[1][h][kk], bf, acc[1][h]);
                acc[2][h] = MFMA16(ag,            bf, acc[2][h]);
                acc[3][h] = MFMA16(ob[kk % 3][h], bf, acc[3][h]);
            }
            #pragma unroll
            for (int h = 0; h < 2; ++h)
                ob[kk % 3][h] = *(const bf16x8*)(obase + (size_t)(16 * h) * KEXT
                                                 + 32 * ((kk + 3) % 9));
        }
        {
            float hh[4];
            #pragma unroll
            for (int r = 0; r < 4; ++r) {
                float iv = acc[0][0][r], fv = acc[1][0][r];
                float gv = acc[2][0][r], ov = acc[3][0][r];
                float cc = sigm(fv) * c[0][r] + sigm(iv) * tanh_f(gv);
                c[0][r] = cc;
                hh[r] = sigm(ov) * tanh_f(cc);
            }
            int dim = 32 * wv + 4 * quad;
            *(unsigned*)&hx[1][l15][dim]     = pk2(hh[0], hh[1]);
            *(unsigned*)&hx[1][l15][dim + 2] = pk2(hh[2], hh[3]);
        }
        #pragma unroll
        for (int s = 0; s < 5; ++s) wrf[s] = *(const bf16x8*)(wbase + 32 * s);
        {
            float hh[4];
            #pragma unroll
            for (int r = 0; r < 4; ++r) {
                float iv = acc[0][1][r], fv = acc[1][1][r];
                float gv = acc[2][1][r], ov = acc[3][1][r];
                float cc = sigm(fv) * c[1][r] + sigm(iv) * tanh_f(gv);
                c[1][r] = cc;
                hh[r] = sigm(ov) * tanh_f(cc);
            }
            int dim = 32 * wv + 16 + 4 * quad;
            *(unsigned*)&hx[1][l15][dim]     = pk2(hh[0], hh[1]);
            *(unsigned*)&hx[1][l15][dim + 2] = pk2(hh[2], hh[3]);
        }
        #pragma unroll
        for (int s = 5; s < 9; ++s) wrf[s] = *(const bf16x8*)(wbase + 32 * s);
    }
    bar_lds();   // B1: h_1 visible; wrf/ob loads stay in flight

    // ========== time loop (rotated): iter i emits y_i; computes gates_{i+1}, h_{i+2} ====
    for (int i = 0; i < TSTEPS; ++i) {
        const bf16_t (*cur)[HS] = hx[(i + 1) & 1];   // h_{i+1}: read by Z_i and G_{i+1}
        bf16_t (*nxt)[HS]       = hx[i & 1];         // h_{i+2} destination

        // -- Z_i: z_i = relu(h_{i+1} @ Wo1ext^T); Wo1 from wrf (no global loads);
        //         zb[3] rolling same-slot distance-3; za 2 parallel chains --
        {
            bf16x8 zb[3];
            #pragma unroll
            for (int s = 0; s < 3; ++s)
                zb[s] = *(const bf16x8*)&cur[l15][32 * s + 8 * quad];
            f32x4 za0 = zero4, za1 = zero4;
            #pragma unroll
            for (int kk = 0; kk < 9; ++kk) {
                if (kk & 1) za1 = MFMA16(wrf[kk], zb[kk % 3], za1);
                else        za0 = MFMA16(wrf[kk], zb[kk % 3], za0);
                if (kk + 3 <= 8)
                    zb[kk % 3] = *(const bf16x8*)&cur[l15][32 * (kk + 3) + 8 * quad];
            }
            f32x4 za = za0 + za1;
            int zd = 16 * wv + 4 * quad;
            *(unsigned*)&zbuf[l15][zd]     = pk2(fmaxf(za[0], 0.f), fmaxf(za[1], 0.f));
            *(unsigned*)&zbuf[l15][zd + 2] = pk2(fmaxf(za[2], 0.f), fmaxf(za[3], 0.f));
        }
        bar_lds();   // B2: z complete; ob wrap loads stay in flight

        // -- G_{i+1} kk0..7 (independent of Y_i) + Y_i in ONE straight-line region:
        //    the compiler interleaves Y's reads/MFMAs into G's lgkmcnt waits --
        f32x4 acc[4][2];
        #pragma unroll
        for (int g = 0; g < 4; ++g) { acc[g][0] = zero4; acc[g][1] = zero4; }

        #pragma unroll
        for (int kk = 0; kk < 8; ++kk) {
            int ko = 32 * kk + 8 * quad;
            bf16x8 bf = *(const bf16x8*)&cur[l15][ko];
            #pragma unroll
            for (int h = 0; h < 2; ++h) {
                bf16x8 ag = *(const bf16x8*)&wg[32 * wv + 16 * h + l15][ko];
                acc[0][h] = MFMA16(af[0][h][kk], bf, acc[0][h]);
                acc[1][h] = MFMA16(af[1][h][kk], bf, acc[1][h]);
                acc[2][h] = MFMA16(ag,            bf, acc[2][h]);
                acc[3][h] = MFMA16(ob[kk % 3][h], bf, acc[3][h]);
            }
            // refill consumed slot (WAR orders load after MFMAs; kk=5,6,7 load slice 8
            // and next-t slices 0,1 -> cross-phase slack)
            #pragma unroll
            for (int h = 0; h < 2; ++h)
                ob[kk % 3][h] = *(const bf16x8*)(obase + (size_t)(16 * h) * KEXT
                                                 + 32 * ((kk + 3) % 9));
        }

        // -- Y_i: y_i = z @ Wo2ext^T (all waves, redundant); xf <- x_{i+1}; rotate store --
        {
            f32x4 ya0 = zero4, ya1 = zero4;
            #pragma unroll
            for (int kk = 0; kk < 4; ++kk) {
                int ko = 32 * kk + 8 * quad;
                bf16x8 w2 = *(const bf16x8*)&wo2l[l15][ko];
                bf16x8 zz = *(const bf16x8*)&zbuf[l15][ko];
                if (kk & 2) ya1 = MFMA16(w2, zz, ya1);
                else        ya0 = MFMA16(w2, zz, ya0);
            }
            f32x4 yv = ya0 + ya1;
            float y0 = yv[0] + bo2v0, y1 = yv[1] + bo2v1, y2 = yv[2] + bo2v2;
            if (wv == (i & 7) && quad == 0) {   // rotate storer: ack never blocks a barrier
                float* op = out + ((size_t)(gb + l15) * TSTEPS + i) * 3;
                op[0] = y0; op[1] = y1; op[2] = y2;
            }
            if (quad == 0) {
                xf[0] = (bf16_t)y0; xf[1] = (bf16_t)y1; xf[2] = (bf16_t)y2; xf[3] = (bf16_t)1.f;
            }
        }

        // -- G_{i+1} kk=8: B = xf (x_{i+1}); o-slice 8 from ob[2] (loaded at kk=5) --
        {
            #pragma unroll
            for (int h = 0; h < 2; ++h) {
                // wg read past col 263 aliases next row's cols; B zero there -> harmless
                bf16x8 ag8 = *(const bf16x8*)&wg[32 * wv + 16 * h + l15][256 + 8 * quad];
                acc[0][h] = MFMA16(af[0][h][8], xf, acc[0][h]);
                acc[1][h] = MFMA16(af[1][h][8], xf, acc[1][h]);
                acc[2][h] = MFMA16(ag8,         xf, acc[2][h]);
                acc[3][h] = MFMA16(ob[2][h],    xf, acc[3][h]);
            }
            // refill slot 2 with next-t slice 2
            #pragma unroll
            for (int h = 0; h < 2; ++h)
                ob[2][h] = *(const bf16x8*)(obase + (size_t)(16 * h) * KEXT + 32 * 2);
        }

        // -- cell update + write h_{i+2}; wrf burst mid-cell (acc dying; loads get
        //    cell+barrier+Z-ramp of slack before next Z consumes) --
        {
            float hh[4];
            #pragma unroll
            for (int r = 0; r < 4; ++r) {
                float iv = acc[0][0][r], fv = acc[1][0][r];
                float gv = acc[2][0][r], ov = acc[3][0][r];
                float cc = sigm(fv) * c[0][r] + sigm(iv) * tanh_f(gv);
                c[0][r] = cc;
                hh[r] = sigm(ov) * tanh_f(cc);
            }
            int dim = 32 * wv + 4 * quad;
            *(unsigned*)&nxt[l15][dim]     = pk2(hh[0], hh[1]);
            *(unsigned*)&nxt[l15][dim + 2] = pk2(hh[2], hh[3]);
        }
        #pragma unroll
        for (int s = 0; s < 5; ++s) wrf[s] = *(const bf16x8*)(wbase + 32 * s);
        {
            float hh[4];
            #pragma unroll
            for (int r = 0; r < 4; ++r) {
                float iv = acc[0][1][r], fv = acc[1][1][r];
                float gv = acc[2][1][r], ov = acc[3][1][r];
                float cc = sigm(fv) * c[1][r] + sigm(iv) * tanh_f(gv);
                c[1][r] = cc;
                hh[r] = sigm(ov) * tanh_f(cc);
            }
            int dim = 32 * wv + 16 + 4 * quad;
            *(unsigned*)&nxt[l15][dim]     = pk2(hh[0], hh[1]);
            *(unsigned*)&nxt[l15][dim + 2] = pk2(hh[2], hh[3]);
        }
        #pragma unroll
        for (int s = 5; s < 9; ++s) wrf[s] = *(const bf16x8*)(wbase + 32 * s);
        bar_lds();   // B1: h_{i+2} visible; wrf/ob loads stay in flight
    }
}

extern "C" void kernel_launch(void* const* d_in, const int* in_sizes, int n_in,
                              void* d_out, int out_size, void* d_ws, size_t ws_size,
                              hipStream_t stream)
{
    const float* meta = (const float*)d_in[0];
    const float* W1   = (const float*)d_in[2];
    const float* b1   = (const float*)d_in[3];
    const float* W2   = (const float*)d_in[4];
    const float* b2   = (const float*)d_in[5];
    const float* Wih  = (const float*)d_in[6];
    const float* Whh  = (const float*)d_in[7];
    const float* bih  = (const float*)d_in[8];
    const float* bhh  = (const float*)d_in[9];
    const float* Wo1  = (const float*)d_in[10];
    const float* bo1  = (const float*)d_in[11];
    const float* Wo2  = (const float*)d_in[12];
    const float* bo2  = (const float*)d_in[13];
    bf16_t* ws  = (bf16_t*)d_ws;
    float*  out = (float*)d_out;

    prep_kernel<<<dim3((WS_ELEMS + 255) / 256), dim3(256), 0, stream>>>(
        W2, b2, Wih, Whh, bih, bhh, Wo1, bo1, Wo2, ws);
    lstm_main<<<dim3(4096 / TILE_B), dim3(512), 0, stream>>>(
        meta, W1, b1, bo2, ws, out);
}